// Round 2
// baseline (135.704 us; speedup 1.0000x reference)
//
#include <hip/hip_runtime.h>
#include <hip/hip_bf16.h>

typedef short short8 __attribute__((ext_vector_type(8)));
typedef float f32x4  __attribute__((ext_vector_type(4)));
typedef unsigned int u32;

static constexpr int NB  = 4;
static constexpr int NC  = 256;
static constexpr int NHW = 4096;
static constexpr int ND  = 64;
static constexpr int SPLIT = 8;
static constexpr int JITER = NHW / 64 / SPLIT;   // 8
static constexpr float SHIFT = 12.0f;            // fixed exp shift (cancels)

__device__ inline float bfbits2f(unsigned short u) {
    union { unsigned int i; float f; } x; x.i = ((unsigned int)u) << 16; return x.f;
}

// async global->LDS, 16B per lane; LDS dest must be wave-uniform base.
__device__ static inline void gload16(const void* g, void* l) {
    __builtin_amdgcn_global_load_lds(
        (const __attribute__((address_space(1))) u32*)g,
        (__attribute__((address_space(3))) u32*)l, 16, 0, 0);
}

// ---------------------------------------------------------------------------
// Kernel 0: weights -> bf16.  wqkv_bf[192][256] (q|k|v), wsa_bf[256][64].
// ---------------------------------------------------------------------------
__global__ __launch_bounds__(256) void wcvt_kernel(
    const float* __restrict__ wq, const float* __restrict__ wk,
    const float* __restrict__ wv, const float* __restrict__ wsa,
    __hip_bfloat16* __restrict__ wqkv_bf, __hip_bfloat16* __restrict__ wsa_bf)
{
    const int idx = blockIdx.x * 256 + threadIdx.x;
    if (idx < 192 * 256) {
        const int row = idx >> 8, col = idx & 255;
        const float* src = row < 64 ? wq : (row < 128 ? wk : wv);
        wqkv_bf[idx] = __float2bfloat16(src[(row & 63) * 256 + col]);
    } else {
        const int i = idx - 192 * 256;
        wsa_bf[i] = __float2bfloat16(wsa[i]);
    }
}

// ---------------------------------------------------------------------------
// Kernel 1: QKV projection via MFMA.  Grid (NB, NHW/32), 512 threads.
// (unchanged from round 1)
// ---------------------------------------------------------------------------
__global__ __launch_bounds__(512) void qkv_kernel(
    const float* __restrict__ x, const __hip_bfloat16* __restrict__ wqkv,
    const float* __restrict__ bq, const float* __restrict__ bk,
    const float* __restrict__ bv,
    __hip_bfloat16* __restrict__ qt, __hip_bfloat16* __restrict__ kt,
    __hip_bfloat16* __restrict__ vd)
{
    const int b  = blockIdx.x;
    const int n0 = blockIdx.y * 32;
    __shared__ __align__(16) __hip_bfloat16 xs[32][256];   // 16 KB swizzled
    __shared__ __align__(16) __hip_bfloat16 vt_s[64][40];  // 5 KB
    __shared__ __align__(16) __hip_bfloat16 qs [32][72];   // 4.6 KB
    __shared__ __align__(16) __hip_bfloat16 ks2[32][72];   // 4.6 KB

    const int t  = threadIdx.x;
    const int tn = t & 31;
    const int cq = t >> 5;          // 0..15

    const float* xb = x + (size_t)b * NC * NHW + n0;
    #pragma unroll
    for (int kblk = 0; kblk < 4; ++kblk) {
        const int c0 = cq * 4 + kblk * 64;
        __hip_bfloat16 pk[4];
        #pragma unroll
        for (int j = 0; j < 4; ++j)
            pk[j] = __float2bfloat16(xb[(size_t)(c0 + j) * NHW + tn]);
        const int kk = (c0 >> 3) ^ (tn & 7);
        *(uint2*)&xs[tn][kk * 8 + (c0 & 7)] = *(uint2*)pk;
    }
    __syncthreads();

    const int w    = t >> 6;        // 0..7
    const int wm   = w >> 2;        // 0..1 : 16-pixel half
    const int wn   = w & 3;         // 0..3 : 48-col group
    const int lane = t & 63;
    const int c    = lane & 15;
    const int q    = lane >> 4;

    f32x4 acc[3];
    #pragma unroll
    for (int nt = 0; nt < 3; ++nt) acc[nt] = (f32x4){0.f, 0.f, 0.f, 0.f};

    const int row = wm * 16 + c;
    #pragma unroll
    for (int kc = 0; kc < 8; ++kc) {
        const int kk = (kc * 4 + q) ^ (row & 7);
        const short8 a = *(const short8*)&xs[row][kk * 8];
        #pragma unroll
        for (int nt = 0; nt < 3; ++nt) {
            const short8 bfr = *(const short8*)(wqkv
                + (size_t)(wn * 48 + nt * 16 + c) * 256 + kc * 32 + q * 8);
            acc[nt] = __builtin_amdgcn_mfma_f32_16x16x32_bf16(a, bfr, acc[nt], 0, 0, 0);
        }
    }

    #pragma unroll
    for (int nt = 0; nt < 3; ++nt) {
        const int j0   = wn * 48 + nt * 16;
        const int sel  = j0 >> 6;
        const int colr = (j0 & 63) + c;
        const float bias = (sel == 0 ? bq : (sel == 1 ? bk : bv))[colr];
        if (sel < 2) {
            __hip_bfloat16 (*dst)[72] = (sel == 0 ? qs : ks2);
            #pragma unroll
            for (int r = 0; r < 4; ++r)
                dst[wm * 16 + q * 4 + r][colr] =
                    __float2bfloat16(acc[nt][r] + bias);
        } else {
            #pragma unroll
            for (int r = 0; r < 4; ++r)
                vt_s[colr][wm * 16 + q * 4 + r] =
                    __float2bfloat16(acc[nt][r] + bias);
        }
    }
    __syncthreads();
    // writeout: 768 short8 tasks over 512 threads (0:v 1:q 2:k)
    for (int task = t; task < 768; task += 512) {
        const int which = task >> 8;
        const int i = task & 255;
        if (which == 0) {
            const int d = i >> 2, nc8 = (i & 3) * 8;
            *(short8*)(vd + ((size_t)(b * ND) + d) * NHW + n0 + nc8) =
                *(const short8*)&vt_s[d][nc8];
        } else {
            __hip_bfloat16* dst = (which == 1) ? qt : kt;
            const __hip_bfloat16 (*src)[72] = (which == 1) ? qs : ks2;
            const int n = i >> 3, d8 = (i & 7) * 8;
            *(short8*)(dst + ((size_t)(b * NHW) + n0 + n) * ND + d8) =
                *(const short8*)&src[n][d8];
        }
    }
}

// ---------------------------------------------------------------------------
// Kernel 2: flash attention, S^T-form MFMA, no-max softmax (fixed shift).
// Grid (NB, NHW/128, SPLIT=8) = 1024 blocks, 256 thr, 4 blocks/CU.
// NEW this round:
//  - K/V staged via global_load_lds (16B) into LINEAR [64][64] LDS tiles,
//    bank-conflict-free via XOR pre-swizzle of the per-lane GLOBAL source
//    address (unit ^= row&7) + matching XOR on the ds_read side.
//  - Double-buffered tiles, stage(t+1) issued before compute(t), ONE
//    __syncthreads per iter (its implicit vmcnt(0) drain completes staging).
//  - P buffer shrunk to [4][32][32] (8 KB) via j-half split PV; 8B-granule
//    XOR swizzle keeps writes/reads ~2-way.  Total LDS = 40 KB exactly.
//  - No K/V prefetch registers at all (-32 VGPR vs round 1).
// ---------------------------------------------------------------------------
__global__ __launch_bounds__(256, 4) void attn_kernel(
    const __hip_bfloat16* __restrict__ qt,
    const __hip_bfloat16* __restrict__ kt,
    const __hip_bfloat16* __restrict__ vd,
    __hip_bfloat16* __restrict__ O_part, float* __restrict__ l_part)
{
    const int b  = blockIdx.x;
    const int q0 = blockIdx.y * 128;
    const int s  = blockIdx.z;

    __shared__ __align__(16) __hip_bfloat16 kbuf[2][64][64];  // 16 KB
    __shared__ __align__(16) __hip_bfloat16 vbuf[2][64][64];  // 16 KB
    __shared__ __align__(16) __hip_bfloat16 ps[4][32][32];    //  8 KB

    const int t    = threadIdx.x;
    const int w    = t >> 6;
    const int lane = t & 63;
    const int c    = lane & 15;
    const int q    = lane >> 4;
    const int sw   = c & 7;           // read-side row XOR (row&7 == c&7)

    // staging lane constants: lane -> (row_local = lane>>3, unit = lane&7)
    const int rl   = lane >> 3;       // 0..7
    const int u    = lane & 7;
    const int swz8 = ((u ^ rl) & 7) * 8;  // pre-swizzled element offset

    const __hip_bfloat16* kt_b = kt + (size_t)b * NHW * ND;
    const __hip_bfloat16* vd_b = vd + (size_t)b * ND * NHW;

    // Q fragments (B-operand for S^T): lane [n=c][k=8q+j]
    short8 qf[2][2];
    #pragma unroll
    for (int mt = 0; mt < 2; ++mt)
        #pragma unroll
        for (int ch = 0; ch < 2; ++ch)
            qf[mt][ch] = *(const short8*)(qt
                + ((size_t)(b * NHW) + q0 + w * 32 + mt * 16 + c) * ND
                + ch * 32 + q * 8);

    f32x4 O[2][4];
    #pragma unroll
    for (int mt = 0; mt < 2; ++mt)
        #pragma unroll
        for (int dt = 0; dt < 4; ++dt)
            O[mt][dt] = (f32x4){0.f, 0.f, 0.f, 0.f};
    float lsum[2] = {0.f, 0.f};

    const int j0base = s * (NHW / SPLIT);

    // prologue: stage tile 0 -> buffer 0 (async), then barrier (drains vmcnt)
    #pragma unroll
    for (int i = 0; i < 2; ++i) {
        const int r0 = w * 16 + i * 8;
        gload16(kt_b + (size_t)(j0base + r0 + rl) * ND + swz8, &kbuf[0][r0][0]);
        gload16(vd_b + (size_t)(r0 + rl) * NHW + j0base + swz8, &vbuf[0][r0][0]);
    }
    __syncthreads();

    for (int it = 0; it < JITER; ++it) {
        const int cur = it & 1;
        if (it + 1 < JITER) {                  // async prefetch next tile
            const int j0 = j0base + (it + 1) * 64;
            #pragma unroll
            for (int i = 0; i < 2; ++i) {
                const int r0 = w * 16 + i * 8;
                gload16(kt_b + (size_t)(j0 + r0 + rl) * ND + swz8,
                        &kbuf[cur ^ 1][r0][0]);
                gload16(vd_b + (size_t)(r0 + rl) * NHW + j0 + swz8,
                        &vbuf[cur ^ 1][r0][0]);
            }
        }

        // compute on buf[cur]; PV per 32-j half so ps only holds one half
        #pragma unroll
        for (int jh = 0; jh < 2; ++jh) {
            #pragma unroll
            for (int jtl = 0; jtl < 2; ++jtl) {
                const int rk = (jh * 2 + jtl) * 16 + c;
                const int u0 = q ^ sw;
                const short8 kf0 = *(const short8*)&kbuf[cur][rk][u0 * 8];
                const short8 kf1 = *(const short8*)&kbuf[cur][rk][(u0 ^ 4) * 8];
                #pragma unroll
                for (int mt = 0; mt < 2; ++mt) {
                    f32x4 acc = (f32x4){0.f, 0.f, 0.f, 0.f};
                    acc = __builtin_amdgcn_mfma_f32_16x16x32_bf16(kf0, qf[mt][0], acc, 0, 0, 0);
                    acc = __builtin_amdgcn_mfma_f32_16x16x32_bf16(kf1, qf[mt][1], acc, 0, 0, 0);
                    __hip_bfloat16 pk[4];
                    float ls = 0.f;
                    #pragma unroll
                    for (int r = 0; r < 4; ++r) {
                        const float p = __expf(acc[r] - SHIFT);
                        ls += p;
                        pk[r] = __float2bfloat16(p);
                    }
                    lsum[mt] += ls;
                    // 8B sub-unit su = jtl*4+q, stored at su^sw
                    *(uint2*)&ps[w][mt * 16 + c][((jtl * 4 + q) ^ sw) * 4] =
                        *(uint2*)pk;
                }
            }
            // PV for this half: af = P[row][8q..8q+7] from swizzled ps
            short8 af[2];
            #pragma unroll
            for (int mt = 0; mt < 2; ++mt) {
                union { uint2 u2[2]; short8 s8; } cv;
                cv.u2[0] = *(const uint2*)&ps[w][mt * 16 + c][((2 * q)     ^ sw) * 4];
                cv.u2[1] = *(const uint2*)&ps[w][mt * 16 + c][((2 * q + 1) ^ sw) * 4];
                af[mt] = cv.s8;
            }
            #pragma unroll
            for (int dt = 0; dt < 4; ++dt) {
                const int rv = dt * 16 + c;
                const short8 vf = *(const short8*)
                    &vbuf[cur][rv][((jh * 4 + q) ^ sw) * 8];
                #pragma unroll
                for (int mt = 0; mt < 2; ++mt)
                    O[mt][dt] = __builtin_amdgcn_mfma_f32_16x16x32_bf16(af[mt], vf, O[mt][dt], 0, 0, 0);
            }
        }
        __syncthreads();   // drains my stage (vmcnt) + everyone's compute
    }

    // epilogue
    const size_t sb = (size_t)(s * NB + b);
    #pragma unroll
    for (int mt = 0; mt < 2; ++mt) {
        float lv = lsum[mt];
        lv += __shfl_xor(lv, 16);
        lv += __shfl_xor(lv, 32);
        if (lane < 16)
            l_part[sb * NHW + q0 + w * 32 + mt * 16 + c] = lv;
    }
    #pragma unroll
    for (int mt = 0; mt < 2; ++mt)
        #pragma unroll
        for (int dt = 0; dt < 4; ++dt)
            #pragma unroll
            for (int r = 0; r < 4; ++r) {
                const int row = q0 + w * 32 + mt * 16 + q * 4 + r;
                O_part[(sb * NHW + row) * ND + dt * 16 + c] =
                    __float2bfloat16(O[mt][dt][r]);
            }
}

// ---------------------------------------------------------------------------
// Kernel 3 (fused combine + out): unchanged from round 1.
// ---------------------------------------------------------------------------
__global__ __launch_bounds__(512) void out_kernel(
    const __hip_bfloat16* __restrict__ O_part, const float* __restrict__ l_part,
    const __hip_bfloat16* __restrict__ wsa_bf,
    const float* __restrict__ bsa, const float* __restrict__ g,
    const float* __restrict__ x, float* __restrict__ out)
{
    const int b  = blockIdx.x;
    const int n0 = blockIdx.y * 32;
    const int t  = threadIdx.x;

    __shared__ __align__(16) __hip_bfloat16 sat_s[32][72];  // 4.6 KB
    __shared__ __align__(16) float os[256][33];             // 33.8 KB

    // ---- Phase A: combine O_part/l_part -> sat tile (bf16 in LDS) ----
    {
        const int n  = t >> 4;            // 0..31
        const int d4 = (t & 15) * 4;      // 0..60
        const size_t bn = (size_t)b * NHW + n0 + n;
        float num[4] = {0.f, 0.f, 0.f, 0.f};
        float den = 0.f;
        #pragma unroll
        for (int s = 0; s < SPLIT; ++s) {
            den += l_part[(size_t)s * NB * NHW + bn];
            const unsigned short* op = (const unsigned short*)(O_part
                + ((size_t)s * NB * NHW + bn) * ND + d4);
            ushort4 u = *(const ushort4*)op;
            num[0] += bfbits2f(u.x); num[1] += bfbits2f(u.y);
            num[2] += bfbits2f(u.z); num[3] += bfbits2f(u.w);
        }
        const float inv = 1.f / den;
        __hip_bfloat16 o4[4];
        #pragma unroll
        for (int j = 0; j < 4; ++j) o4[j] = __float2bfloat16(num[j] * inv);
        *(uint2*)&sat_s[n][d4] = *(uint2*)o4;
    }
    __syncthreads();

    // ---- Phase B: MFMA wsa @ sat -> os (f32 + bias) ----
    {
        const int w    = t >> 6;
        const int lane = t & 63;
        const int c    = lane & 15;
        const int q    = lane >> 4;

        short8 bfr[2][2];
        #pragma unroll
        for (int nt = 0; nt < 2; ++nt)
            #pragma unroll
            for (int ch = 0; ch < 2; ++ch)
                bfr[nt][ch] = *(const short8*)&sat_s[nt * 16 + c][ch * 32 + q * 8];

        short8 af[2][2];
        #pragma unroll
        for (int mt = 0; mt < 2; ++mt)
            #pragma unroll
            for (int ch = 0; ch < 2; ++ch)
                af[mt][ch] = *(const short8*)(wsa_bf
                    + ((size_t)(w * 32 + mt * 16 + c)) * ND + ch * 32 + q * 8);

        #pragma unroll
        for (int mt = 0; mt < 2; ++mt) {
            float biasr[4];
            #pragma unroll
            for (int r = 0; r < 4; ++r)
                biasr[r] = bsa[w * 32 + mt * 16 + q * 4 + r];
            #pragma unroll
            for (int nt = 0; nt < 2; ++nt) {
                f32x4 a = (f32x4){0.f, 0.f, 0.f, 0.f};
                a = __builtin_amdgcn_mfma_f32_16x16x32_bf16(af[mt][0], bfr[nt][0], a, 0, 0, 0);
                a = __builtin_amdgcn_mfma_f32_16x16x32_bf16(af[mt][1], bfr[nt][1], a, 0, 0, 0);
                #pragma unroll
                for (int r = 0; r < 4; ++r)
                    os[w * 32 + mt * 16 + q * 4 + r][nt * 16 + c] = a[r] + biasr[r];
            }
        }
    }
    __syncthreads();

    // ---- Phase C: out = gamma*os + x, vectorized float4 ----
    const float gamma = g[0];
    #pragma unroll
    for (int pass = 0; pass < 4; ++pass) {
        const int row = pass * 64 + (t >> 3);   // channel 0..255
        const int nq  = (t & 7) * 4;            // pixel offset 0..28
        const size_t oi = ((size_t)(b * NC) + row) * NHW + n0 + nq;
        const float4 xv = *(const float4*)(x + oi);
        float4 ov;
        ov.x = gamma * os[row][nq + 0] + xv.x;
        ov.y = gamma * os[row][nq + 1] + xv.y;
        ov.z = gamma * os[row][nq + 2] + xv.z;
        ov.w = gamma * os[row][nq + 3] + xv.w;
        *(float4*)(out + oi) = ov;
    }
}

// ---------------------------------------------------------------------------
extern "C" void kernel_launch(void* const* d_in, const int* in_sizes, int n_in,
                              void* d_out, int out_size, void* d_ws, size_t ws_size,
                              hipStream_t stream)
{
    const float* x     = (const float*)d_in[0];
    const float* wq    = (const float*)d_in[1];
    const float* bq    = (const float*)d_in[2];
    const float* wk    = (const float*)d_in[3];
    const float* bk    = (const float*)d_in[4];
    const float* wv    = (const float*)d_in[5];
    const float* bv    = (const float*)d_in[6];
    const float* wsa   = (const float*)d_in[7];
    const float* bsa   = (const float*)d_in[8];
    const float* gamma = (const float*)d_in[9];
    float* out = (float*)d_out;

    char* p = (char*)d_ws;
    __hip_bfloat16* wqkv_bf = (__hip_bfloat16*)p; p += (size_t)128 << 10;
    __hip_bfloat16* wsa_bf  = (__hip_bfloat16*)p; p += (size_t)128 << 10;
    __hip_bfloat16* qt = (__hip_bfloat16*)p; p += (size_t)2 << 20;
    __hip_bfloat16* kt = (__hip_bfloat16*)p; p += (size_t)2 << 20;
    __hip_bfloat16* vd = (__hip_bfloat16*)p; p += (size_t)2 << 20;
    __hip_bfloat16* O_part = (__hip_bfloat16*)p; p += (size_t)16 << 20;
    float* l_part = (float*)p; p += (size_t)1 << 20;

    wcvt_kernel<<<dim3(256), 256, 0, stream>>>(wq, wk, wv, wsa, wqkv_bf, wsa_bf);
    qkv_kernel<<<dim3(NB, NHW / 32), 512, 0, stream>>>(
        x, wqkv_bf, bq, bk, bv, qt, kt, vd);
    attn_kernel<<<dim3(NB, NHW / 128, SPLIT), 256, 0, stream>>>(
        qt, kt, vd, O_part, l_part);
    out_kernel<<<dim3(NB, NHW / 32), 512, 0, stream>>>(
        O_part, l_part, wsa_bf, bsa, gamma, x, out);
}

// Round 4
// 135.103 us; speedup vs baseline: 1.0045x; 1.0045x over previous
//
#include <hip/hip_runtime.h>
#include <hip/hip_bf16.h>

typedef short short8 __attribute__((ext_vector_type(8)));
typedef float f32x4  __attribute__((ext_vector_type(4)));
typedef float f32x16 __attribute__((ext_vector_type(16)));
typedef unsigned int u32;

static constexpr int NB  = 4;
static constexpr int NC  = 256;
static constexpr int NHW = 4096;
static constexpr int ND  = 64;
static constexpr int SPLIT = 8;
static constexpr int JITER = NHW / 64 / SPLIT;   // 8
static constexpr float SHIFT = 12.0f;            // fixed exp shift (cancels)

__device__ inline float bfbits2f(unsigned short u) {
    union { unsigned int i; float f; } x; x.i = ((unsigned int)u) << 16; return x.f;
}

// ---------------------------------------------------------------------------
// Kernel 0: weights -> bf16.  wqkv_bf[192][256] (q|k|v), wsa_bf[256][64].
// ---------------------------------------------------------------------------
__global__ __launch_bounds__(256) void wcvt_kernel(
    const float* __restrict__ wq, const float* __restrict__ wk,
    const float* __restrict__ wv, const float* __restrict__ wsa,
    __hip_bfloat16* __restrict__ wqkv_bf, __hip_bfloat16* __restrict__ wsa_bf)
{
    const int idx = blockIdx.x * 256 + threadIdx.x;
    if (idx < 192 * 256) {
        const int row = idx >> 8, col = idx & 255;
        const float* src = row < 64 ? wq : (row < 128 ? wk : wv);
        wqkv_bf[idx] = __float2bfloat16(src[(row & 63) * 256 + col]);
    } else {
        const int i = idx - 192 * 256;
        wsa_bf[i] = __float2bfloat16(wsa[i]);
    }
}

// ---------------------------------------------------------------------------
// Kernel 1: QKV projection via MFMA.  Grid (NB, NHW/32), 512 threads.
// (unchanged from round 1)
// ---------------------------------------------------------------------------
__global__ __launch_bounds__(512) void qkv_kernel(
    const float* __restrict__ x, const __hip_bfloat16* __restrict__ wqkv,
    const float* __restrict__ bq, const float* __restrict__ bk,
    const float* __restrict__ bv,
    __hip_bfloat16* __restrict__ qt, __hip_bfloat16* __restrict__ kt,
    __hip_bfloat16* __restrict__ vd)
{
    const int b  = blockIdx.x;
    const int n0 = blockIdx.y * 32;
    __shared__ __align__(16) __hip_bfloat16 xs[32][256];   // 16 KB swizzled
    __shared__ __align__(16) __hip_bfloat16 vt_s[64][40];  // 5 KB
    __shared__ __align__(16) __hip_bfloat16 qs [32][72];   // 4.6 KB
    __shared__ __align__(16) __hip_bfloat16 ks2[32][72];   // 4.6 KB

    const int t  = threadIdx.x;
    const int tn = t & 31;
    const int cq = t >> 5;          // 0..15

    const float* xb = x + (size_t)b * NC * NHW + n0;
    #pragma unroll
    for (int kblk = 0; kblk < 4; ++kblk) {
        const int c0 = cq * 4 + kblk * 64;
        __hip_bfloat16 pk[4];
        #pragma unroll
        for (int j = 0; j < 4; ++j)
            pk[j] = __float2bfloat16(xb[(size_t)(c0 + j) * NHW + tn]);
        const int kk = (c0 >> 3) ^ (tn & 7);
        *(uint2*)&xs[tn][kk * 8 + (c0 & 7)] = *(uint2*)pk;
    }
    __syncthreads();

    const int w    = t >> 6;        // 0..7
    const int wm   = w >> 2;        // 0..1 : 16-pixel half
    const int wn   = w & 3;         // 0..3 : 48-col group
    const int lane = t & 63;
    const int c    = lane & 15;
    const int q    = lane >> 4;

    f32x4 acc[3];
    #pragma unroll
    for (int nt = 0; nt < 3; ++nt) acc[nt] = (f32x4){0.f, 0.f, 0.f, 0.f};

    const int row = wm * 16 + c;
    #pragma unroll
    for (int kc = 0; kc < 8; ++kc) {
        const int kk = (kc * 4 + q) ^ (row & 7);
        const short8 a = *(const short8*)&xs[row][kk * 8];
        #pragma unroll
        for (int nt = 0; nt < 3; ++nt) {
            const short8 bfr = *(const short8*)(wqkv
                + (size_t)(wn * 48 + nt * 16 + c) * 256 + kc * 32 + q * 8);
            acc[nt] = __builtin_amdgcn_mfma_f32_16x16x32_bf16(a, bfr, acc[nt], 0, 0, 0);
        }
    }

    #pragma unroll
    for (int nt = 0; nt < 3; ++nt) {
        const int j0   = wn * 48 + nt * 16;
        const int sel  = j0 >> 6;
        const int colr = (j0 & 63) + c;
        const float bias = (sel == 0 ? bq : (sel == 1 ? bk : bv))[colr];
        if (sel < 2) {
            __hip_bfloat16 (*dst)[72] = (sel == 0 ? qs : ks2);
            #pragma unroll
            for (int r = 0; r < 4; ++r)
                dst[wm * 16 + q * 4 + r][colr] =
                    __float2bfloat16(acc[nt][r] + bias);
        } else {
            #pragma unroll
            for (int r = 0; r < 4; ++r)
                vt_s[colr][wm * 16 + q * 4 + r] =
                    __float2bfloat16(acc[nt][r] + bias);
        }
    }
    __syncthreads();
    // writeout: 768 short8 tasks over 512 threads (0:v 1:q 2:k)
    for (int task = t; task < 768; task += 512) {
        const int which = task >> 8;
        const int i = task & 255;
        if (which == 0) {
            const int d = i >> 2, nc8 = (i & 3) * 8;
            *(short8*)(vd + ((size_t)(b * ND) + d) * NHW + n0 + nc8) =
                *(const short8*)&vt_s[d][nc8];
        } else {
            __hip_bfloat16* dst = (which == 1) ? qt : kt;
            const __hip_bfloat16 (*src)[72] = (which == 1) ? qs : ks2;
            const int n = i >> 3, d8 = (i & 7) * 8;
            *(short8*)(dst + ((size_t)(b * NHW) + n0 + n) * ND + d8) =
                *(const short8*)&src[n][d8];
        }
    }
}

// ---------------------------------------------------------------------------
// Kernel 2: flash attention — round-1 structure (register prefetch, 2
// barriers/iter, ps[i][j] LDS P-buffer, 16x16 PV) with ONE surgical change:
// QK^T now uses mfma_f32_32x32x16_bf16.  Lane (li=lane&31, hi=lane>>5)
// holds S^T[j = (r&3)+8*(r>>2)+4*hi + 32*jh][i = li]; P is exp'd and
// stored to ps[w][i=li][j] as u32 pairs (j even).  The CONSUMER (PV reads
// af = ps[w][i][q*8..]) is byte-identical to the verified round-1 kernel,
// so this round validates the 32x32 operand/output conventions in isolation.
// ---------------------------------------------------------------------------
__global__ __launch_bounds__(256, 4) void attn_kernel(
    const __hip_bfloat16* __restrict__ qt,
    const __hip_bfloat16* __restrict__ kt,
    const __hip_bfloat16* __restrict__ vd,
    __hip_bfloat16* __restrict__ O_part, float* __restrict__ l_part)
{
    const int b  = blockIdx.x;
    const int q0 = blockIdx.y * 128;
    const int s  = blockIdx.z;

    __shared__ __align__(16) __hip_bfloat16 ks [64][72];
    __shared__ __align__(16) __hip_bfloat16 vts[64][72];
    __shared__ __align__(16) __hip_bfloat16 ps [4][32][72];

    const int t    = threadIdx.x;
    const int w    = t >> 6;
    const int lane = t & 63;
    const int c    = lane & 15;
    const int q    = lane >> 4;
    const int li   = lane & 31;
    const int hi   = lane >> 5;

    // Q fragments as 32x32 B-operand: qf32[kc] = Q[q0+w*32+li][kc*16+hi*8..]
    short8 qf32[4];
    #pragma unroll
    for (int kc = 0; kc < 4; ++kc)
        qf32[kc] = *(const short8*)(qt
            + ((size_t)(b * NHW) + q0 + w * 32 + li) * ND + kc * 16 + hi * 8);

    f32x4 O[2][4];
    #pragma unroll
    for (int mt = 0; mt < 2; ++mt)
        #pragma unroll
        for (int dt = 0; dt < 4; ++dt)
            O[mt][dt] = (f32x4){0.f, 0.f, 0.f, 0.f};
    float lsum = 0.f;

    const int row_s = t >> 3;          // staging row 0..31
    const int c8    = (t & 7) * 8;
    short8 kpre[2], vpre[2];
    {
        const int j0 = s * (NHW / SPLIT);
        kpre[0] = *(const short8*)(kt + ((size_t)(b * NHW) + j0 + row_s) * ND + c8);
        kpre[1] = *(const short8*)(kt + ((size_t)(b * NHW) + j0 + 32 + row_s) * ND + c8);
        vpre[0] = *(const short8*)(vd + ((size_t)(b * ND) + row_s) * NHW + j0 + c8);
        vpre[1] = *(const short8*)(vd + ((size_t)(b * ND) + 32 + row_s) * NHW + j0 + c8);
    }

    for (int it = 0; it < JITER; ++it) {
        __syncthreads();                       // prior iter done with tiles
        *(short8*)&ks [row_s     ][c8] = kpre[0];
        *(short8*)&ks [32 + row_s][c8] = kpre[1];
        *(short8*)&vts[row_s     ][c8] = vpre[0];
        *(short8*)&vts[32 + row_s][c8] = vpre[1];
        if (it + 1 < JITER) {                  // prefetch next tile
            const int j0 = s * (NHW / SPLIT) + (it + 1) * 64;
            kpre[0] = *(const short8*)(kt + ((size_t)(b * NHW) + j0 + row_s) * ND + c8);
            kpre[1] = *(const short8*)(kt + ((size_t)(b * NHW) + j0 + 32 + row_s) * ND + c8);
            vpre[0] = *(const short8*)(vd + ((size_t)(b * ND) + row_s) * NHW + j0 + c8);
            vpre[1] = *(const short8*)(vd + ((size_t)(b * ND) + 32 + row_s) * NHW + j0 + c8);
        }
        __syncthreads();

        // ---- S^T via 32x32x16 MFMA + exp + ps store (the NEW part) ----
        #pragma unroll
        for (int jh = 0; jh < 2; ++jh) {
            f32x16 acc;
            #pragma unroll
            for (int r = 0; r < 16; ++r) acc[r] = 0.f;
            #pragma unroll
            for (int kc = 0; kc < 4; ++kc) {
                const short8 kf = *(const short8*)
                    &ks[jh * 32 + li][kc * 16 + hi * 8];
                acc = __builtin_amdgcn_mfma_f32_32x32x16_bf16(kf, qf32[kc], acc, 0, 0, 0);
            }
            #pragma unroll
            for (int r2 = 0; r2 < 8; ++r2) {
                const float p0 = __expf(acc[2 * r2]     - SHIFT);
                const float p1 = __expf(acc[2 * r2 + 1] - SHIFT);
                lsum += p0 + p1;
                __hip_bfloat16 pk2[2];
                pk2[0] = __float2bfloat16(p0);
                pk2[1] = __float2bfloat16(p1);
                const int jp = jh * 32 + 2 * (r2 & 1) + 8 * (r2 >> 1) + 4 * hi;
                *(u32*)&ps[w][li][jp] = *(const u32*)pk2;
            }
        }

        // ---- PV: byte-identical to round-1 (verified consumer) ----
        short8 af[2][2];
        #pragma unroll
        for (int mt = 0; mt < 2; ++mt) {
            af[mt][0] = *(const short8*)&ps[w][mt * 16 + c][q * 8];
            af[mt][1] = *(const short8*)&ps[w][mt * 16 + c][32 + q * 8];
        }
        #pragma unroll
        for (int dt = 0; dt < 4; ++dt) {
            const short8 vf0 = *(const short8*)&vts[dt * 16 + c][q * 8];
            const short8 vf1 = *(const short8*)&vts[dt * 16 + c][32 + q * 8];
            #pragma unroll
            for (int mt = 0; mt < 2; ++mt) {
                O[mt][dt] = __builtin_amdgcn_mfma_f32_16x16x32_bf16(af[mt][0], vf0, O[mt][dt], 0, 0, 0);
                O[mt][dt] = __builtin_amdgcn_mfma_f32_16x16x32_bf16(af[mt][1], vf1, O[mt][dt], 0, 0, 0);
            }
        }
    }

    // epilogue
    const size_t sb = (size_t)(s * NB + b);
    lsum += __shfl_xor(lsum, 32);
    if (lane < 32)
        l_part[sb * NHW + q0 + w * 32 + li] = lsum;

    #pragma unroll
    for (int mt = 0; mt < 2; ++mt)
        #pragma unroll
        for (int dt = 0; dt < 4; ++dt)
            #pragma unroll
            for (int r = 0; r < 4; ++r) {
                const int row = q0 + w * 32 + mt * 16 + q * 4 + r;
                O_part[(sb * NHW + row) * ND + dt * 16 + c] =
                    __float2bfloat16(O[mt][dt][r]);
            }
}

// ---------------------------------------------------------------------------
// Kernel 3 (fused combine + out): unchanged.
// ---------------------------------------------------------------------------
__global__ __launch_bounds__(512) void out_kernel(
    const __hip_bfloat16* __restrict__ O_part, const float* __restrict__ l_part,
    const __hip_bfloat16* __restrict__ wsa_bf,
    const float* __restrict__ bsa, const float* __restrict__ g,
    const float* __restrict__ x, float* __restrict__ out)
{
    const int b  = blockIdx.x;
    const int n0 = blockIdx.y * 32;
    const int t  = threadIdx.x;

    __shared__ __align__(16) __hip_bfloat16 sat_s[32][72];  // 4.6 KB
    __shared__ __align__(16) float os[256][33];             // 33.8 KB

    // ---- Phase A: combine O_part/l_part -> sat tile (bf16 in LDS) ----
    {
        const int n  = t >> 4;            // 0..31
        const int d4 = (t & 15) * 4;      // 0..60
        const size_t bn = (size_t)b * NHW + n0 + n;
        float num[4] = {0.f, 0.f, 0.f, 0.f};
        float den = 0.f;
        #pragma unroll
        for (int s = 0; s < SPLIT; ++s) {
            den += l_part[(size_t)s * NB * NHW + bn];
            const unsigned short* op = (const unsigned short*)(O_part
                + ((size_t)s * NB * NHW + bn) * ND + d4);
            ushort4 u = *(const ushort4*)op;
            num[0] += bfbits2f(u.x); num[1] += bfbits2f(u.y);
            num[2] += bfbits2f(u.z); num[3] += bfbits2f(u.w);
        }
        const float inv = 1.f / den;
        __hip_bfloat16 o4[4];
        #pragma unroll
        for (int j = 0; j < 4; ++j) o4[j] = __float2bfloat16(num[j] * inv);
        *(uint2*)&sat_s[n][d4] = *(uint2*)o4;
    }
    __syncthreads();

    // ---- Phase B: MFMA wsa @ sat -> os (f32 + bias) ----
    {
        const int w    = t >> 6;
        const int lane = t & 63;
        const int c    = lane & 15;
        const int q    = lane >> 4;

        short8 bfr[2][2];
        #pragma unroll
        for (int nt = 0; nt < 2; ++nt)
            #pragma unroll
            for (int ch = 0; ch < 2; ++ch)
                bfr[nt][ch] = *(const short8*)&sat_s[nt * 16 + c][ch * 32 + q * 8];

        short8 af[2][2];
        #pragma unroll
        for (int mt = 0; mt < 2; ++mt)
            #pragma unroll
            for (int ch = 0; ch < 2; ++ch)
                af[mt][ch] = *(const short8*)(wsa_bf
                    + ((size_t)(w * 32 + mt * 16 + c)) * ND + ch * 32 + q * 8);

        #pragma unroll
        for (int mt = 0; mt < 2; ++mt) {
            float biasr[4];
            #pragma unroll
            for (int r = 0; r < 4; ++r)
                biasr[r] = bsa[w * 32 + mt * 16 + q * 4 + r];
            #pragma unroll
            for (int nt = 0; nt < 2; ++nt) {
                f32x4 a = (f32x4){0.f, 0.f, 0.f, 0.f};
                a = __builtin_amdgcn_mfma_f32_16x16x32_bf16(af[mt][0], bfr[nt][0], a, 0, 0, 0);
                a = __builtin_amdgcn_mfma_f32_16x16x32_bf16(af[mt][1], bfr[nt][1], a, 0, 0, 0);
                #pragma unroll
                for (int r = 0; r < 4; ++r)
                    os[w * 32 + mt * 16 + q * 4 + r][nt * 16 + c] = a[r] + biasr[r];
            }
        }
    }
    __syncthreads();

    // ---- Phase C: out = gamma*os + x, vectorized float4 ----
    const float gamma = g[0];
    #pragma unroll
    for (int pass = 0; pass < 4; ++pass) {
        const int row = pass * 64 + (t >> 3);   // channel 0..255
        const int nq  = (t & 7) * 4;            // pixel offset 0..28
        const size_t oi = ((size_t)(b * NC) + row) * NHW + n0 + nq;
        const float4 xv = *(const float4*)(x + oi);
        float4 ov;
        ov.x = gamma * os[row][nq + 0] + xv.x;
        ov.y = gamma * os[row][nq + 1] + xv.y;
        ov.z = gamma * os[row][nq + 2] + xv.z;
        ov.w = gamma * os[row][nq + 3] + xv.w;
        *(float4*)(out + oi) = ov;
    }
}

// ---------------------------------------------------------------------------
extern "C" void kernel_launch(void* const* d_in, const int* in_sizes, int n_in,
                              void* d_out, int out_size, void* d_ws, size_t ws_size,
                              hipStream_t stream)
{
    const float* x     = (const float*)d_in[0];
    const float* wq    = (const float*)d_in[1];
    const float* bq    = (const float*)d_in[2];
    const float* wk    = (const float*)d_in[3];
    const float* bk    = (const float*)d_in[4];
    const float* wv    = (const float*)d_in[5];
    const float* bv    = (const float*)d_in[6];
    const float* wsa   = (const float*)d_in[7];
    const float* bsa   = (const float*)d_in[8];
    const float* gamma = (const float*)d_in[9];
    float* out = (float*)d_out;

    char* p = (char*)d_ws;
    __hip_bfloat16* wqkv_bf = (__hip_bfloat16*)p; p += (size_t)128 << 10;
    __hip_bfloat16* wsa_bf  = (__hip_bfloat16*)p; p += (size_t)128 << 10;
    __hip_bfloat16* qt = (__hip_bfloat16*)p; p += (size_t)2 << 20;
    __hip_bfloat16* kt = (__hip_bfloat16*)p; p += (size_t)2 << 20;
    __hip_bfloat16* vd = (__hip_bfloat16*)p; p += (size_t)2 << 20;
    __hip_bfloat16* O_part = (__hip_bfloat16*)p; p += (size_t)16 << 20;
    float* l_part = (float*)p; p += (size_t)1 << 20;

    wcvt_kernel<<<dim3(256), 256, 0, stream>>>(wq, wk, wv, wsa, wqkv_bf, wsa_bf);
    qkv_kernel<<<dim3(NB, NHW / 32), 512, 0, stream>>>(
        x, wqkv_bf, bq, bk, bv, qt, kt, vd);
    attn_kernel<<<dim3(NB, NHW / 128, SPLIT), 256, 0, stream>>>(
        qt, kt, vd, O_part, l_part);
    out_kernel<<<dim3(NB, NHW / 32), 512, 0, stream>>>(
        O_part, l_part, wsa_bf, bsa, gamma, x, out);
}

// Round 5
// 135.093 us; speedup vs baseline: 1.0045x; 1.0001x over previous
//
#include <hip/hip_runtime.h>
#include <hip/hip_bf16.h>

typedef short short8 __attribute__((ext_vector_type(8)));
typedef float f32x4  __attribute__((ext_vector_type(4)));
typedef float f32x16 __attribute__((ext_vector_type(16)));
typedef unsigned int u32;

static constexpr int NB  = 4;
static constexpr int NC  = 256;
static constexpr int NHW = 4096;
static constexpr int ND  = 64;
static constexpr int SPLIT = 8;
static constexpr int JITER = NHW / 64 / SPLIT;   // 8
static constexpr float SHIFT = 12.0f;            // fixed exp shift (cancels)

__device__ inline float bfbits2f(unsigned short u) {
    union { unsigned int i; float f; } x; x.i = ((unsigned int)u) << 16; return x.f;
}

// pack two floats to bf16 pair (a -> low 16, b -> high 16), RNE via HIP cast
__device__ inline u32 pack2bf(float a, float b) {
    union { __hip_bfloat16 h; unsigned short s; } ua, ub;
    ua.h = __float2bfloat16(a);
    ub.h = __float2bfloat16(b);
    return (u32)ua.s | ((u32)ub.s << 16);
}

// ---------------------------------------------------------------------------
// Kernel 0: weights -> bf16.  wqkv_bf[192][256] (q|k|v), wsa_bf[256][64].
// ---------------------------------------------------------------------------
__global__ __launch_bounds__(256) void wcvt_kernel(
    const float* __restrict__ wq, const float* __restrict__ wk,
    const float* __restrict__ wv, const float* __restrict__ wsa,
    __hip_bfloat16* __restrict__ wqkv_bf, __hip_bfloat16* __restrict__ wsa_bf)
{
    const int idx = blockIdx.x * 256 + threadIdx.x;
    if (idx < 192 * 256) {
        const int row = idx >> 8, col = idx & 255;
        const float* src = row < 64 ? wq : (row < 128 ? wk : wv);
        wqkv_bf[idx] = __float2bfloat16(src[(row & 63) * 256 + col]);
    } else {
        const int i = idx - 192 * 256;
        wsa_bf[i] = __float2bfloat16(wsa[i]);
    }
}

// ---------------------------------------------------------------------------
// Kernel 1: QKV projection via MFMA.  Grid (NB, NHW/32), 512 threads.
// (unchanged)
// ---------------------------------------------------------------------------
__global__ __launch_bounds__(512) void qkv_kernel(
    const float* __restrict__ x, const __hip_bfloat16* __restrict__ wqkv,
    const float* __restrict__ bq, const float* __restrict__ bk,
    const float* __restrict__ bv,
    __hip_bfloat16* __restrict__ qt, __hip_bfloat16* __restrict__ kt,
    __hip_bfloat16* __restrict__ vd)
{
    const int b  = blockIdx.x;
    const int n0 = blockIdx.y * 32;
    __shared__ __align__(16) __hip_bfloat16 xs[32][256];   // 16 KB swizzled
    __shared__ __align__(16) __hip_bfloat16 vt_s[64][40];  // 5 KB
    __shared__ __align__(16) __hip_bfloat16 qs [32][72];   // 4.6 KB
    __shared__ __align__(16) __hip_bfloat16 ks2[32][72];   // 4.6 KB

    const int t  = threadIdx.x;
    const int tn = t & 31;
    const int cq = t >> 5;          // 0..15

    const float* xb = x + (size_t)b * NC * NHW + n0;
    #pragma unroll
    for (int kblk = 0; kblk < 4; ++kblk) {
        const int c0 = cq * 4 + kblk * 64;
        __hip_bfloat16 pk[4];
        #pragma unroll
        for (int j = 0; j < 4; ++j)
            pk[j] = __float2bfloat16(xb[(size_t)(c0 + j) * NHW + tn]);
        const int kk = (c0 >> 3) ^ (tn & 7);
        *(uint2*)&xs[tn][kk * 8 + (c0 & 7)] = *(uint2*)pk;
    }
    __syncthreads();

    const int w    = t >> 6;        // 0..7
    const int wm   = w >> 2;        // 0..1 : 16-pixel half
    const int wn   = w & 3;         // 0..3 : 48-col group
    const int lane = t & 63;
    const int c    = lane & 15;
    const int q    = lane >> 4;

    f32x4 acc[3];
    #pragma unroll
    for (int nt = 0; nt < 3; ++nt) acc[nt] = (f32x4){0.f, 0.f, 0.f, 0.f};

    const int row = wm * 16 + c;
    #pragma unroll
    for (int kc = 0; kc < 8; ++kc) {
        const int kk = (kc * 4 + q) ^ (row & 7);
        const short8 a = *(const short8*)&xs[row][kk * 8];
        #pragma unroll
        for (int nt = 0; nt < 3; ++nt) {
            const short8 bfr = *(const short8*)(wqkv
                + (size_t)(wn * 48 + nt * 16 + c) * 256 + kc * 32 + q * 8);
            acc[nt] = __builtin_amdgcn_mfma_f32_16x16x32_bf16(a, bfr, acc[nt], 0, 0, 0);
        }
    }

    #pragma unroll
    for (int nt = 0; nt < 3; ++nt) {
        const int j0   = wn * 48 + nt * 16;
        const int sel  = j0 >> 6;
        const int colr = (j0 & 63) + c;
        const float bias = (sel == 0 ? bq : (sel == 1 ? bk : bv))[colr];
        if (sel < 2) {
            __hip_bfloat16 (*dst)[72] = (sel == 0 ? qs : ks2);
            #pragma unroll
            for (int r = 0; r < 4; ++r)
                dst[wm * 16 + q * 4 + r][colr] =
                    __float2bfloat16(acc[nt][r] + bias);
        } else {
            #pragma unroll
            for (int r = 0; r < 4; ++r)
                vt_s[colr][wm * 16 + q * 4 + r] =
                    __float2bfloat16(acc[nt][r] + bias);
        }
    }
    __syncthreads();
    // writeout: 768 short8 tasks over 512 threads (0:v 1:q 2:k)
    for (int task = t; task < 768; task += 512) {
        const int which = task >> 8;
        const int i = task & 255;
        if (which == 0) {
            const int d = i >> 2, nc8 = (i & 3) * 8;
            *(short8*)(vd + ((size_t)(b * ND) + d) * NHW + n0 + nc8) =
                *(const short8*)&vt_s[d][nc8];
        } else {
            __hip_bfloat16* dst = (which == 1) ? qt : kt;
            const __hip_bfloat16 (*src)[72] = (which == 1) ? qs : ks2;
            const int n = i >> 3, d8 = (i & 7) * 8;
            *(short8*)(dst + ((size_t)(b * NHW) + n0 + n) * ND + d8) =
                *(const short8*)&src[n][d8];
        }
    }
}

// ---------------------------------------------------------------------------
// Kernel 2: flash attention — full 32x32 form, P entirely in registers.
// Grid (NB, NHW/128, SPLIT=8) = 1024 blocks, 256 thr, 4 blocks/CU.
// Validated (round 4): mfma32 A/B lane k = kc*16 + hi*8 + e;
//                      C/D row = (r&3)+8*(r>>2)+4*hi, col = li.
// S^T = mfma32(K,Q): lane (li,hi) holds P[qrow=li][j=m(r,hi)+32jh].
// exp -> explicit bf16 pair pack (NO asm cvt_pk) -> lane^32 half-exchange
// (__shfl_xor) builds PV A-frags [qrow=li][j=base+8hi+e] directly.
// PV = mfma32(P,V) accumulates O[qrow][d] with V rows = d (vts layout).
// ps LDS buffer GONE: LDS = ks+vts = 18 KB.
// ---------------------------------------------------------------------------
__global__ __launch_bounds__(256, 4) void attn_kernel(
    const __hip_bfloat16* __restrict__ qt,
    const __hip_bfloat16* __restrict__ kt,
    const __hip_bfloat16* __restrict__ vd,
    __hip_bfloat16* __restrict__ O_part, float* __restrict__ l_part)
{
    const int b  = blockIdx.x;
    const int q0 = blockIdx.y * 128;
    const int s  = blockIdx.z;

    __shared__ __align__(16) __hip_bfloat16 ks [64][72];
    __shared__ __align__(16) __hip_bfloat16 vts[64][72];

    const int t    = threadIdx.x;
    const int w    = t >> 6;
    const int lane = t & 63;
    const int li   = lane & 31;
    const int hi   = lane >> 5;

    // Q fragments (B-operand): qf32[kc] = Q[q0+w*32+li][kc*16+hi*8 ..+8]
    short8 qf32[4];
    #pragma unroll
    for (int kc = 0; kc < 4; ++kc)
        qf32[kc] = *(const short8*)(qt
            + ((size_t)(b * NHW) + q0 + w * 32 + li) * ND + kc * 16 + hi * 8);

    f32x16 Ov[2];
    #pragma unroll
    for (int dh = 0; dh < 2; ++dh)
        #pragma unroll
        for (int r = 0; r < 16; ++r) Ov[dh][r] = 0.f;
    float lsum = 0.f;

    const int row_s = t >> 3;          // staging row 0..31
    const int c8    = (t & 7) * 8;
    short8 kpre[2], vpre[2];
    {
        const int j0 = s * (NHW / SPLIT);
        kpre[0] = *(const short8*)(kt + ((size_t)(b * NHW) + j0 + row_s) * ND + c8);
        kpre[1] = *(const short8*)(kt + ((size_t)(b * NHW) + j0 + 32 + row_s) * ND + c8);
        vpre[0] = *(const short8*)(vd + ((size_t)(b * ND) + row_s) * NHW + j0 + c8);
        vpre[1] = *(const short8*)(vd + ((size_t)(b * ND) + 32 + row_s) * NHW + j0 + c8);
    }

    for (int it = 0; it < JITER; ++it) {
        __syncthreads();                       // prior iter done with tiles
        *(short8*)&ks [row_s     ][c8] = kpre[0];
        *(short8*)&ks [32 + row_s][c8] = kpre[1];
        *(short8*)&vts[row_s     ][c8] = vpre[0];
        *(short8*)&vts[32 + row_s][c8] = vpre[1];
        if (it + 1 < JITER) {                  // prefetch next tile
            const int j0 = s * (NHW / SPLIT) + (it + 1) * 64;
            kpre[0] = *(const short8*)(kt + ((size_t)(b * NHW) + j0 + row_s) * ND + c8);
            kpre[1] = *(const short8*)(kt + ((size_t)(b * NHW) + j0 + 32 + row_s) * ND + c8);
            vpre[0] = *(const short8*)(vd + ((size_t)(b * ND) + row_s) * NHW + j0 + c8);
            vpre[1] = *(const short8*)(vd + ((size_t)(b * ND) + 32 + row_s) * NHW + j0 + c8);
        }
        __syncthreads();

        #pragma unroll
        for (int jh = 0; jh < 2; ++jh) {
            // ---- S^T via 32x32x16 MFMA (validated round 4) ----
            f32x16 acc;
            #pragma unroll
            for (int r = 0; r < 16; ++r) acc[r] = 0.f;
            #pragma unroll
            for (int kc = 0; kc < 4; ++kc) {
                const short8 kf = *(const short8*)
                    &ks[jh * 32 + li][kc * 16 + hi * 8];
                acc = __builtin_amdgcn_mfma_f32_32x32x16_bf16(kf, qf32[kc], acc, 0, 0, 0);
            }

            // ---- exp + pack; W[r2] = (P[j=m(2r2,hi)], P[j=m(2r2+1,hi)]) ----
            // m(r,hi) = (r&3)+8*(r>>2)+4*hi  -> W[0]=(4hi,4hi+1) W[1]=(4hi+2,4hi+3)
            // W[2]=(8+4hi,..) W[3]=(10+4hi,..) W[4..7] same +16.
            u32 W[8];
            #pragma unroll
            for (int r2 = 0; r2 < 8; ++r2) {
                const float p0 = __expf(acc[2 * r2]     - SHIFT);
                const float p1 = __expf(acc[2 * r2 + 1] - SHIFT);
                lsum += p0 + p1;
                W[r2] = pack2bf(p0, p1);
            }

            // ---- lane^32 half-exchange -> PV A-frags ----
            // a0 covers j = jh*32 + [0..15]: lane hi holds j = 8hi..8hi+7:
            //  hi=0: (0,1)(2,3)(4,5)(6,7) = ownW0, ownW1, otherW0, otherW1
            //  hi=1: (8,9)(10,11)(12,13)(14,15) = otherW2, otherW3, ownW2, ownW3
            // a1 same with W[4..7] for j = jh*32 + [16..31].
            u32 sw[8];
            #pragma unroll
            for (int r2 = 0; r2 < 8; ++r2)
                sw[r2] = (u32)__shfl_xor((int)W[r2], 32);
            union { u32 uu[4]; short8 s8; } a0, a1;
            a0.uu[0] = hi ? sw[2] : W[0];
            a0.uu[1] = hi ? sw[3] : W[1];
            a0.uu[2] = hi ? W[2]  : sw[0];
            a0.uu[3] = hi ? W[3]  : sw[1];
            a1.uu[0] = hi ? sw[6] : W[4];
            a1.uu[1] = hi ? sw[7] : W[5];
            a1.uu[2] = hi ? W[6]  : sw[4];
            a1.uu[3] = hi ? W[7]  : sw[5];

            // ---- PV: Ov[dh] += P[.,j-slice] * V[d=dh*32+li][j-slice] ----
            #pragma unroll
            for (int dh = 0; dh < 2; ++dh) {
                const short8 vf0 = *(const short8*)
                    &vts[dh * 32 + li][jh * 32 + hi * 8];
                Ov[dh] = __builtin_amdgcn_mfma_f32_32x32x16_bf16(a0.s8, vf0, Ov[dh], 0, 0, 0);
                const short8 vf1 = *(const short8*)
                    &vts[dh * 32 + li][jh * 32 + 16 + hi * 8];
                Ov[dh] = __builtin_amdgcn_mfma_f32_32x32x16_bf16(a1.s8, vf1, Ov[dh], 0, 0, 0);
            }
        }
    }

    // ---- epilogue ----
    const size_t sb = (size_t)(s * NB + b);
    lsum += __shfl_xor(lsum, 32);
    if (lane < 32)
        l_part[sb * NHW + q0 + w * 32 + li] = lsum;

    #pragma unroll
    for (int dh = 0; dh < 2; ++dh)
        #pragma unroll
        for (int r = 0; r < 16; ++r) {
            const int i = (r & 3) + 8 * (r >> 2) + 4 * hi;   // qrow in wave tile
            O_part[(sb * NHW + q0 + w * 32 + i) * ND + dh * 32 + li] =
                __float2bfloat16(Ov[dh][r]);
        }
}

// ---------------------------------------------------------------------------
// Kernel 3 (fused combine + out): unchanged.
// ---------------------------------------------------------------------------
__global__ __launch_bounds__(512) void out_kernel(
    const __hip_bfloat16* __restrict__ O_part, const float* __restrict__ l_part,
    const __hip_bfloat16* __restrict__ wsa_bf,
    const float* __restrict__ bsa, const float* __restrict__ g,
    const float* __restrict__ x, float* __restrict__ out)
{
    const int b  = blockIdx.x;
    const int n0 = blockIdx.y * 32;
    const int t  = threadIdx.x;

    __shared__ __align__(16) __hip_bfloat16 sat_s[32][72];  // 4.6 KB
    __shared__ __align__(16) float os[256][33];             // 33.8 KB

    // ---- Phase A: combine O_part/l_part -> sat tile (bf16 in LDS) ----
    {
        const int n  = t >> 4;            // 0..31
        const int d4 = (t & 15) * 4;      // 0..60
        const size_t bn = (size_t)b * NHW + n0 + n;
        float num[4] = {0.f, 0.f, 0.f, 0.f};
        float den = 0.f;
        #pragma unroll
        for (int s = 0; s < SPLIT; ++s) {
            den += l_part[(size_t)s * NB * NHW + bn];
            const unsigned short* op = (const unsigned short*)(O_part
                + ((size_t)s * NB * NHW + bn) * ND + d4);
            ushort4 u = *(const ushort4*)op;
            num[0] += bfbits2f(u.x); num[1] += bfbits2f(u.y);
            num[2] += bfbits2f(u.z); num[3] += bfbits2f(u.w);
        }
        const float inv = 1.f / den;
        __hip_bfloat16 o4[4];
        #pragma unroll
        for (int j = 0; j < 4; ++j) o4[j] = __float2bfloat16(num[j] * inv);
        *(uint2*)&sat_s[n][d4] = *(uint2*)o4;
    }
    __syncthreads();

    // ---- Phase B: MFMA wsa @ sat -> os (f32 + bias) ----
    {
        const int w    = t >> 6;
        const int lane = t & 63;
        const int c    = lane & 15;
        const int q    = lane >> 4;

        short8 bfr[2][2];
        #pragma unroll
        for (int nt = 0; nt < 2; ++nt)
            #pragma unroll
            for (int ch = 0; ch < 2; ++ch)
                bfr[nt][ch] = *(const short8*)&sat_s[nt * 16 + c][ch * 32 + q * 8];

        short8 af[2][2];
        #pragma unroll
        for (int mt = 0; mt < 2; ++mt)
            #pragma unroll
            for (int ch = 0; ch < 2; ++ch)
                af[mt][ch] = *(const short8*)(wsa_bf
                    + ((size_t)(w * 32 + mt * 16 + c)) * ND + ch * 32 + q * 8);

        #pragma unroll
        for (int mt = 0; mt < 2; ++mt) {
            float biasr[4];
            #pragma unroll
            for (int r = 0; r < 4; ++r)
                biasr[r] = bsa[w * 32 + mt * 16 + q * 4 + r];
            #pragma unroll
            for (int nt = 0; nt < 2; ++nt) {
                f32x4 a = (f32x4){0.f, 0.f, 0.f, 0.f};
                a = __builtin_amdgcn_mfma_f32_16x16x32_bf16(af[mt][0], bfr[nt][0], a, 0, 0, 0);
                a = __builtin_amdgcn_mfma_f32_16x16x32_bf16(af[mt][1], bfr[nt][1], a, 0, 0, 0);
                #pragma unroll
                for (int r = 0; r < 4; ++r)
                    os[w * 32 + mt * 16 + q * 4 + r][nt * 16 + c] = a[r] + biasr[r];
            }
        }
    }
    __syncthreads();

    // ---- Phase C: out = gamma*os + x, vectorized float4 ----
    const float gamma = g[0];
    #pragma unroll
    for (int pass = 0; pass < 4; ++pass) {
        const int row = pass * 64 + (t >> 3);   // channel 0..255
        const int nq  = (t & 7) * 4;            // pixel offset 0..28
        const size_t oi = ((size_t)(b * NC) + row) * NHW + n0 + nq;
        const float4 xv = *(const float4*)(x + oi);
        float4 ov;
        ov.x = gamma * os[row][nq + 0] + xv.x;
        ov.y = gamma * os[row][nq + 1] + xv.y;
        ov.z = gamma * os[row][nq + 2] + xv.z;
        ov.w = gamma * os[row][nq + 3] + xv.w;
        *(float4*)(out + oi) = ov;
    }
}

// ---------------------------------------------------------------------------
extern "C" void kernel_launch(void* const* d_in, const int* in_sizes, int n_in,
                              void* d_out, int out_size, void* d_ws, size_t ws_size,
                              hipStream_t stream)
{
    const float* x     = (const float*)d_in[0];
    const float* wq    = (const float*)d_in[1];
    const float* bq    = (const float*)d_in[2];
    const float* wk    = (const float*)d_in[3];
    const float* bk    = (const float*)d_in[4];
    const float* wv    = (const float*)d_in[5];
    const float* bv    = (const float*)d_in[6];
    const float* wsa   = (const float*)d_in[7];
    const float* bsa   = (const float*)d_in[8];
    const float* gamma = (const float*)d_in[9];
    float* out = (float*)d_out;

    char* p = (char*)d_ws;
    __hip_bfloat16* wqkv_bf = (__hip_bfloat16*)p; p += (size_t)128 << 10;
    __hip_bfloat16* wsa_bf  = (__hip_bfloat16*)p; p += (size_t)128 << 10;
    __hip_bfloat16* qt = (__hip_bfloat16*)p; p += (size_t)2 << 20;
    __hip_bfloat16* kt = (__hip_bfloat16*)p; p += (size_t)2 << 20;
    __hip_bfloat16* vd = (__hip_bfloat16*)p; p += (size_t)2 << 20;
    __hip_bfloat16* O_part = (__hip_bfloat16*)p; p += (size_t)16 << 20;
    float* l_part = (float*)p; p += (size_t)1 << 20;

    wcvt_kernel<<<dim3(256), 256, 0, stream>>>(wq, wk, wv, wsa, wqkv_bf, wsa_bf);
    qkv_kernel<<<dim3(NB, NHW / 32), 512, 0, stream>>>(
        x, wqkv_bf, bq, bk, bv, qt, kt, vd);
    attn_kernel<<<dim3(NB, NHW / 128, SPLIT), 256, 0, stream>>>(
        qt, kt, vd, O_part, l_part);
    out_kernel<<<dim3(NB, NHW / 32), 512, 0, stream>>>(
        O_part, l_part, wsa_bf, bsa, gamma, x, out);
}